// Round 1
// baseline (412.366 us; speedup 1.0000x reference)
//
#include <hip/hip_runtime.h>
#include <math.h>

#define NPTS 500000
#define TSIZE 524288u
#define TMASK (TSIZE - 1u)

struct ResArgs { float r[16]; };

__global__ __launch_bounds__(256) void mhe_kernel(
    const float* __restrict__ x,
    const float* __restrict__ tbl,
    float* __restrict__ out,
    ResArgs ra)
{
    int gid = blockIdx.x * 256 + threadIdx.x;
    int p = gid >> 4;      // point index: 16 consecutive lanes share a point
    int l = gid & 15;      // level index in low bits -> coalesced float2 writes
    if (p >= NPTS) return;

    float x0 = x[p * 3 + 0];
    float x1 = x[p * 3 + 1];
    float x2 = x[p * 3 + 2];
    float res = ra.r[l];   // per-lane kernarg load, L1-broadcast

    float s0 = x0 * res, s1 = x1 * res, s2 = x2 * res;
    float f0 = floorf(s0), f1 = floorf(s1), f2 = floorf(s2);
    float w0 = s0 - f0, w1 = s1 - f1, w2 = s2 - f2;
    unsigned u0 = (unsigned)f0, u1 = (unsigned)f1, u2 = (unsigned)f2;

    // h = (u0+o0)*1 ^ (u1+o1)*P1 ^ (u2+o2)*P2  (uint32 wraparound, exact)
    unsigned a0 = u0,                    a1 = u0 + 1u;
    unsigned b0 = u1 * 2654435761u,      b1 = (u1 + 1u) * 2654435761u;
    unsigned c0 = u2 * 805459861u,       c1 = (u2 + 1u) * 805459861u;

    const float2* t = (const float2*)tbl + (size_t)l * TSIZE;

    float v0a = 1.f - w0, v0b = w0;
    float v1a = 1.f - w1, v1b = w1;
    float v2a = 1.f - w2, v2b = w2;

    float o0 = 0.f, o1 = 0.f;
#pragma unroll
    for (int c = 0; c < 8; ++c) {
        unsigned h = ((c & 1) ? a1 : a0) ^ ((c & 2) ? b1 : b0) ^ ((c & 4) ? c1 : c0);
        float2 f = t[h & TMASK];   // 8 independent 8B gathers, hoisted by unroll
        float wgt = ((c & 1) ? v0b : v0a) * ((c & 2) ? v1b : v1a) * ((c & 4) ? v2b : v2a);
        o0 = fmaf(wgt, f.x, o0);
        o1 = fmaf(wgt, f.y, o1);
    }

    ((float2*)out)[(size_t)p * 16 + l] = make_float2(o0, o1);
}

extern "C" void kernel_launch(void* const* d_in, const int* in_sizes, int n_in,
                              void* d_out, int out_size, void* d_ws, size_t ws_size,
                              hipStream_t stream) {
    const float* x   = (const float*)d_in[0];
    const float* tbl = (const float*)d_in[1];
    float* out = (float*)d_out;

    // Replicate numpy's RES computation bit-for-bit on the HOST (same libm as
    // numpy): b = exp((log(512)-log(16))/15); RES[l] = floor(16 * b**l).
    // Levels 3,6,9,12,15 land exactly on 32/64/128/256/512 in exact math, so a
    // 1-ulp mismatch vs numpy flips floor() -- do NOT compute this on device.
    ResArgs ra;
    double bb = exp((log(512.0) - log(16.0)) / 15.0);
    for (int l = 0; l < 16; ++l)
        ra.r[l] = (float)floor(16.0 * pow(bb, (double)l));

    int total = NPTS * 16;               // 8,000,000 = 31250 * 256 exactly
    int blocks = (total + 255) / 256;
    mhe_kernel<<<blocks, 256, 0, stream>>>(x, tbl, out, ra);
}

// Round 2
// 241.422 us; speedup vs baseline: 1.7081x; 1.7081x over previous
//
#include <hip/hip_runtime.h>
#include <math.h>

#define NPTS 500000
#define TSIZE 524288u
#define TMASK (TSIZE - 1u)
#define CHUNKS 1954  // ceil(NPTS/256)

struct ResArgs { float r[16]; };

// Shared per-(point,level) math: 8 hashed gathers + trilinear blend.
__device__ __forceinline__ float2 mhe_point_level(
    const float* __restrict__ x, const float* __restrict__ tbl,
    int p, int l, float res)
{
    float x0 = x[p * 3 + 0];
    float x1 = x[p * 3 + 1];
    float x2 = x[p * 3 + 2];

    float s0 = x0 * res, s1 = x1 * res, s2 = x2 * res;
    float f0 = floorf(s0), f1 = floorf(s1), f2 = floorf(s2);
    float w0 = s0 - f0, w1 = s1 - f1, w2 = s2 - f2;
    unsigned u0 = (unsigned)f0, u1 = (unsigned)f1, u2 = (unsigned)f2;

    unsigned a0 = u0,               a1 = u0 + 1u;
    unsigned b0 = u1 * 2654435761u, b1 = (u1 + 1u) * 2654435761u;
    unsigned c0 = u2 * 805459861u,  c1 = (u2 + 1u) * 805459861u;

    const float2* t = (const float2*)tbl + (size_t)l * TSIZE;

    float v0a = 1.f - w0, v0b = w0;
    float v1a = 1.f - w1, v1b = w1;
    float v2a = 1.f - w2, v2b = w2;

    float o0 = 0.f, o1 = 0.f;
#pragma unroll
    for (int c = 0; c < 8; ++c) {
        unsigned h = ((c & 1) ? a1 : a0) ^ ((c & 2) ? b1 : b0) ^ ((c & 4) ? c1 : c0);
        float2 f = t[h & TMASK];
        float wgt = ((c & 1) ? v0b : v0a) * ((c & 2) ? v1b : v1a) * ((c & 4) ? v2b : v2a);
        o0 = fmaf(wgt, f.x, o0);
        o1 = fmaf(wgt, f.y, o1);
    }
    return make_float2(o0, o1);
}

// ---- Path 1: XCD-partitioned gather into ws[level][point] ----------------
// blockIdx -> XCD is round-robin (%8) on MI355X (T1 heuristic). Give XCD x
// levels {x, x+8}: each XCD's gather footprint drops from ~48MB to <=8.4MB,
// so the level's 4MB table slice becomes (mostly) L2-resident on its XCD.
__global__ __launch_bounds__(256) void mhe_gather(
    const float* __restrict__ x,
    const float* __restrict__ tbl,
    float2* __restrict__ ws,
    ResArgs ra)
{
    int b = blockIdx.x;
    int xcd = b & 7;
    int i = b >> 3;                 // 0 .. 2*CHUNKS-1
    int l = xcd + ((i & 1) << 3);   // levels {xcd, xcd+8} on this XCD
    int p = (i >> 1) * 256 + threadIdx.x;
    if (p >= NPTS) return;

    float2 o = mhe_point_level(x, tbl, p, l, ra.r[l]);
    ws[(size_t)l * NPTS + p] = o;   // coalesced float2 store
}

// ---- ws[level][point] -> out[point][level] LDS-tile transpose ------------
__global__ __launch_bounds__(256) void mhe_transpose(
    const float2* __restrict__ ws, float2* __restrict__ out)
{
    __shared__ float2 tile[16][65];  // +1 pad: transposed read hits distinct banks
    int p0 = blockIdx.x * 64;
    int t = threadIdx.x;

    int pc = t & 63;
#pragma unroll
    for (int i = 0; i < 4; ++i) {
        int l = (t >> 6) + i * 4;
        int p = p0 + pc;
        if (p < NPTS) tile[l][pc] = ws[(size_t)l * NPTS + p];
    }
    __syncthreads();

#pragma unroll
    for (int i = 0; i < 4; ++i) {
        int pp = (t >> 4) + i * 16;
        int l = t & 15;
        int p = p0 + pp;
        if (p < NPTS) out[(size_t)p * 16 + l] = tile[l][pp];  // 512B/wave contiguous
    }
}

// ---- Fallback: R0 single-kernel direct-out (if ws too small) -------------
__global__ __launch_bounds__(256) void mhe_kernel(
    const float* __restrict__ x,
    const float* __restrict__ tbl,
    float* __restrict__ out,
    ResArgs ra)
{
    int gid = blockIdx.x * 256 + threadIdx.x;
    int p = gid >> 4;
    int l = gid & 15;
    if (p >= NPTS) return;
    float2 o = mhe_point_level(x, tbl, p, l, ra.r[l]);
    ((float2*)out)[(size_t)p * 16 + l] = o;
}

extern "C" void kernel_launch(void* const* d_in, const int* in_sizes, int n_in,
                              void* d_out, int out_size, void* d_ws, size_t ws_size,
                              hipStream_t stream) {
    const float* x   = (const float*)d_in[0];
    const float* tbl = (const float*)d_in[1];
    float* out = (float*)d_out;

    // RES computed on HOST with libm doubles (bit-exact vs numpy): levels
    // 3,6,9,12,15 land exactly on 32/64/128/256/512; device ulp flips floor().
    ResArgs ra;
    double bb = exp((log(512.0) - log(16.0)) / 15.0);
    for (int l = 0; l < 16; ++l)
        ra.r[l] = (float)floor(16.0 * pow(bb, (double)l));

    size_t ws_needed = (size_t)NPTS * 16 * sizeof(float2);  // 64 MB
    if (ws_size >= ws_needed) {
        mhe_gather<<<8 * 2 * CHUNKS, 256, 0, stream>>>(x, tbl, (float2*)d_ws, ra);
        mhe_transpose<<<(NPTS + 63) / 64, 256, 0, stream>>>((const float2*)d_ws,
                                                            (float2*)out);
    } else {
        mhe_kernel<<<(NPTS * 16 + 255) / 256, 256, 0, stream>>>(x, tbl, out, ra);
    }
}

// Round 3
// 228.886 us; speedup vs baseline: 1.8016x; 1.0548x over previous
//
#include <hip/hip_runtime.h>
#include <math.h>

#define NPTS 500000
#define TSIZE 524288u
#define TMASK (TSIZE - 1u)
#define CHUNKS 1954  // ceil(NPTS/256)

struct ResArgs { float r[16]; };

// Per-(point,level): 8 corner gathers with float4 pairing + trilinear blend.
// Corner c bits: (c&1)=dx, (c&2)=dy, (c&4)=dz.
// h = (u0+dx) ^ (u1+dy)*P1 ^ (u2+dz)*P2; idx = h & TMASK (T = 2^19).
// For even u0: h(c|1) = h(c)^1 -> both corners of an x-pair live in one
// aligned float4 at (idx & ~1). For odd u0 lanes, 4 extra float2 gathers.
__device__ __forceinline__ float2 mhe_point_level(
    const float* __restrict__ x, const float* __restrict__ tbl,
    int p, int l, float res)
{
    float x0 = x[p * 3 + 0];
    float x1 = x[p * 3 + 1];
    float x2 = x[p * 3 + 2];

    float s0 = x0 * res, s1 = x1 * res, s2 = x2 * res;
    float f0 = floorf(s0), f1 = floorf(s1), f2 = floorf(s2);
    float w0 = s0 - f0, w1 = s1 - f1, w2 = s2 - f2;
    unsigned u0 = (unsigned)f0, u1 = (unsigned)f1, u2 = (unsigned)f2;

    unsigned b0 = u1 * 2654435761u, b1 = (u1 + 1u) * 2654435761u;
    unsigned c0 = u2 * 805459861u,  c1 = (u2 + 1u) * 805459861u;

    const float2* t  = (const float2*)tbl + (size_t)l * TSIZE;
    const float4* t4 = (const float4*)t;          // TSIZE/2 aligned pairs

    float v0a = 1.f - w0, v0b = w0;
    float v1a = 1.f - w1, v1b = w1;
    float v2a = 1.f - w2, v2b = w2;

    bool odd = (u0 & 1u) != 0u;
    unsigned u0p1 = u0 + 1u;

    float o0 = 0.f, o1 = 0.f;
#pragma unroll
    for (int j = 0; j < 4; ++j) {                 // j bits: (j&1)=dy, (j&2)=dz
        unsigned bc = ((j & 1) ? b1 : b0) ^ ((j & 2) ? c1 : c0);
        unsigned e0 = (u0 ^ bc) & TMASK;          // x-corner 0 entry
        float4 q = t4[e0 >> 1];                   // entries {e0&~1, e0|1}
        float2 lo = make_float2(q.x, q.y);
        float2 hi = make_float2(q.z, q.w);
        float2 fc0 = (e0 & 1u) ? hi : lo;
        float2 fc1 = (e0 & 1u) ? lo : hi;         // valid iff u0 even (e1 = e0^1)
        if (odd) {                                // predicated: only odd lanes load
            unsigned e1 = (u0p1 ^ bc) & TMASK;
            fc1 = t[e1];
        }
        float wyz = ((j & 1) ? v1b : v1a) * ((j & 2) ? v2b : v2a);
        // accumulate in reference corner order c=2j, c=2j+1
        o0 = fmaf(v0a * wyz, fc0.x, o0);
        o1 = fmaf(v0a * wyz, fc0.y, o1);
        o0 = fmaf(v0b * wyz, fc1.x, o0);
        o1 = fmaf(v0b * wyz, fc1.y, o1);
    }
    return make_float2(o0, o1);
}

// ---- XCD-partitioned gather into ws[level][point] ------------------------
// blockIdx%8 -> XCD (MI355X heuristic). XCD x owns levels {x, x+8}.
// Chunk-major: all CHUNKS blocks of level x dispatch before level x+8, so the
// XCD's resident L2 working set is ONE 4MB table slice at a time (no thrash).
__global__ __launch_bounds__(256) void mhe_gather(
    const float* __restrict__ x,
    const float* __restrict__ tbl,
    float2* __restrict__ ws,
    ResArgs ra)
{
    int b = blockIdx.x;
    int xcd = b & 7;
    int i = b >> 3;                     // 0 .. 2*CHUNKS-1
    int half  = i >= CHUNKS;
    int chunk = half ? i - CHUNKS : i;
    int l = xcd + (half << 3);
    int p = chunk * 256 + threadIdx.x;
    if (p >= NPTS) return;

    float2 o = mhe_point_level(x, tbl, p, l, ra.r[l]);
    ws[(size_t)l * NPTS + p] = o;       // coalesced float2 store
}

// ---- ws[level][point] -> out[point][level] LDS-tile transpose ------------
__global__ __launch_bounds__(256) void mhe_transpose(
    const float2* __restrict__ ws, float2* __restrict__ out)
{
    __shared__ float2 tile[16][65];
    int p0 = blockIdx.x * 64;
    int t = threadIdx.x;

    int pc = t & 63;
#pragma unroll
    for (int i = 0; i < 4; ++i) {
        int l = (t >> 6) + i * 4;
        int p = p0 + pc;
        if (p < NPTS) tile[l][pc] = ws[(size_t)l * NPTS + p];
    }
    __syncthreads();

#pragma unroll
    for (int i = 0; i < 4; ++i) {
        int pp = (t >> 4) + i * 16;
        int l = t & 15;
        int p = p0 + pp;
        if (p < NPTS) out[(size_t)p * 16 + l] = tile[l][pp];
    }
}

// ---- Fallback: direct-out single kernel (if ws too small) ----------------
__global__ __launch_bounds__(256) void mhe_kernel(
    const float* __restrict__ x,
    const float* __restrict__ tbl,
    float* __restrict__ out,
    ResArgs ra)
{
    int gid = blockIdx.x * 256 + threadIdx.x;
    int p = gid >> 4;
    int l = gid & 15;
    if (p >= NPTS) return;
    float2 o = mhe_point_level(x, tbl, p, l, ra.r[l]);
    ((float2*)out)[(size_t)p * 16 + l] = o;
}

extern "C" void kernel_launch(void* const* d_in, const int* in_sizes, int n_in,
                              void* d_out, int out_size, void* d_ws, size_t ws_size,
                              hipStream_t stream) {
    const float* x   = (const float*)d_in[0];
    const float* tbl = (const float*)d_in[1];
    float* out = (float*)d_out;

    // RES computed on HOST with libm doubles (bit-exact vs numpy): levels
    // 3,6,9,12,15 land exactly on 32/64/128/256/512; device ulp flips floor().
    ResArgs ra;
    double bb = exp((log(512.0) - log(16.0)) / 15.0);
    for (int l = 0; l < 16; ++l)
        ra.r[l] = (float)floor(16.0 * pow(bb, (double)l));

    size_t ws_needed = (size_t)NPTS * 16 * sizeof(float2);  // 64 MB
    if (ws_size >= ws_needed) {
        mhe_gather<<<8 * 2 * CHUNKS, 256, 0, stream>>>(x, tbl, (float2*)d_ws, ra);
        mhe_transpose<<<(NPTS + 63) / 64, 256, 0, stream>>>((const float2*)d_ws,
                                                            (float2*)out);
    } else {
        mhe_kernel<<<(NPTS * 16 + 255) / 256, 256, 0, stream>>>(x, tbl, out, ra);
    }
}

// Round 4
// 221.228 us; speedup vs baseline: 1.8640x; 1.0346x over previous
//
#include <hip/hip_runtime.h>
#include <math.h>

#define NPTS 500000
#define TSIZE 524288u
#define TMASK (TSIZE - 1u)
#define CHUNKS 1954        // ceil(NPTS/256)
#define SLICE 245          // ceil(CHUNKS/8): pool-level chunks per XCD

struct ResArgs { float r[16]; };

// Per-(point,level): 8 corner gathers with float4 x-pairing + trilinear blend.
__device__ __forceinline__ float2 mhe_point_level(
    const float* __restrict__ x, const float* __restrict__ tbl,
    int p, int l, float res)
{
    float x0 = x[p * 3 + 0];
    float x1 = x[p * 3 + 1];
    float x2 = x[p * 3 + 2];

    float s0 = x0 * res, s1 = x1 * res, s2 = x2 * res;
    float f0 = floorf(s0), f1 = floorf(s1), f2 = floorf(s2);
    float w0 = s0 - f0, w1 = s1 - f1, w2 = s2 - f2;
    unsigned u0 = (unsigned)f0, u1 = (unsigned)f1, u2 = (unsigned)f2;

    unsigned b0 = u1 * 2654435761u, b1 = (u1 + 1u) * 2654435761u;
    unsigned c0 = u2 * 805459861u,  c1 = (u2 + 1u) * 805459861u;

    const float2* t  = (const float2*)tbl + (size_t)l * TSIZE;
    const float4* t4 = (const float4*)t;

    float v0a = 1.f - w0, v0b = w0;
    float v1a = 1.f - w1, v1b = w1;
    float v2a = 1.f - w2, v2b = w2;

    bool odd = (u0 & 1u) != 0u;
    unsigned u0p1 = u0 + 1u;

    float o0 = 0.f, o1 = 0.f;
#pragma unroll
    for (int j = 0; j < 4; ++j) {               // j bits: (j&1)=dy, (j&2)=dz
        unsigned bc = ((j & 1) ? b1 : b0) ^ ((j & 2) ? c1 : c0);
        unsigned e0 = (u0 ^ bc) & TMASK;
        float4 q = t4[e0 >> 1];                 // entries {e0&~1, e0|1}
        float2 lo = make_float2(q.x, q.y);
        float2 hi = make_float2(q.z, q.w);
        float2 fc0 = (e0 & 1u) ? hi : lo;
        float2 fc1 = (e0 & 1u) ? lo : hi;       // valid iff u0 even
        if (odd) {                              // predicated odd-lane fixup
            unsigned e1 = (u0p1 ^ bc) & TMASK;
            fc1 = t[e1];
        }
        float wyz = ((j & 1) ? v1b : v1a) * ((j & 2) ? v2b : v2a);
        o0 = fmaf(v0a * wyz, fc0.x, o0);
        o1 = fmaf(v0a * wyz, fc0.y, o1);
        o0 = fmaf(v0b * wyz, fc1.x, o0);
        o1 = fmaf(v0b * wyz, fc1.y, o1);
    }
    return make_float2(o0, o1);
}

// ---- XCD-balanced gather into ws[level][point] ---------------------------
// blockIdx%8 -> XCD (MI355X round-robin heuristic).
// Phase A (anchor): XCD x owns fine level 8+x (its 4MB slice exactly fills
//   the XCD's L2; all 8 anchors equal work -> no tail).
// Phase B (pool): coarse levels 0..7 each split into 8 chunk-slices, one per
//   XCD, processed LEVEL-MAJOR so all XCDs attack the same level at the same
//   time (slice replicated read-only in each L2; footprint <= 4MB). This
//   spreads each pool level's L2 accesses over all 8 L2s instead of 1.
__global__ __launch_bounds__(256) void mhe_gather(
    const float* __restrict__ x,
    const float* __restrict__ tbl,
    float2* __restrict__ ws,
    ResArgs ra)
{
    int b = blockIdx.x;
    int xcd = b & 7;
    int t = b >> 3;                 // per-XCD task index, issued in order
    int l, chunk;
    if (t < CHUNKS) {               // Phase A: anchor fine level
        l = 8 + xcd;
        chunk = t;
    } else {                        // Phase B: pooled coarse levels
        int u = t - CHUNKS;         // 0 .. 8*SLICE-1
        int pl = u / SLICE;         // pool level 0..7 (level-major)
        int sc = u - pl * SLICE;
        l = pl;
        chunk = xcd * SLICE + sc;   // this XCD's slice of level pl
        if (chunk >= CHUNKS) return;
    }
    int p = chunk * 256 + threadIdx.x;
    if (p >= NPTS) return;

    float2 o = mhe_point_level(x, tbl, p, l, ra.r[l]);
    ws[(size_t)l * NPTS + p] = o;   // coalesced float2 store
}

// ---- ws[level][point] -> out[point][level] LDS-tile transpose ------------
__global__ __launch_bounds__(256) void mhe_transpose(
    const float2* __restrict__ ws, float2* __restrict__ out)
{
    __shared__ float2 tile[16][65];
    int p0 = blockIdx.x * 64;
    int t = threadIdx.x;

    int pc = t & 63;
#pragma unroll
    for (int i = 0; i < 4; ++i) {
        int l = (t >> 6) + i * 4;
        int p = p0 + pc;
        if (p < NPTS) tile[l][pc] = ws[(size_t)l * NPTS + p];
    }
    __syncthreads();

#pragma unroll
    for (int i = 0; i < 4; ++i) {
        int pp = (t >> 4) + i * 16;
        int l = t & 15;
        int p = p0 + pp;
        if (p < NPTS) out[(size_t)p * 16 + l] = tile[l][pp];
    }
}

// ---- Fallback: direct-out single kernel (if ws too small) ----------------
__global__ __launch_bounds__(256) void mhe_kernel(
    const float* __restrict__ x,
    const float* __restrict__ tbl,
    float* __restrict__ out,
    ResArgs ra)
{
    int gid = blockIdx.x * 256 + threadIdx.x;
    int p = gid >> 4;
    int l = gid & 15;
    if (p >= NPTS) return;
    float2 o = mhe_point_level(x, tbl, p, l, ra.r[l]);
    ((float2*)out)[(size_t)p * 16 + l] = o;
}

extern "C" void kernel_launch(void* const* d_in, const int* in_sizes, int n_in,
                              void* d_out, int out_size, void* d_ws, size_t ws_size,
                              hipStream_t stream) {
    const float* x   = (const float*)d_in[0];
    const float* tbl = (const float*)d_in[1];
    float* out = (float*)d_out;

    // RES computed on HOST with libm doubles (bit-exact vs numpy): levels
    // 3,6,9,12,15 land exactly on 32/64/128/256/512; device ulp flips floor().
    ResArgs ra;
    double bb = exp((log(512.0) - log(16.0)) / 15.0);
    for (int l = 0; l < 16; ++l)
        ra.r[l] = (float)floor(16.0 * pow(bb, (double)l));

    size_t ws_needed = (size_t)NPTS * 16 * sizeof(float2);  // 64 MB
    if (ws_size >= ws_needed) {
        int tasks_per_xcd = CHUNKS + 8 * SLICE;   // 1954 + 1960 = 3914
        mhe_gather<<<8 * tasks_per_xcd, 256, 0, stream>>>(x, tbl, (float2*)d_ws, ra);
        mhe_transpose<<<(NPTS + 63) / 64, 256, 0, stream>>>((const float2*)d_ws,
                                                            (float2*)out);
    } else {
        mhe_kernel<<<(NPTS * 16 + 255) / 256, 256, 0, stream>>>(x, tbl, out, ra);
    }
}